// Round 6
// baseline (809.808 us; speedup 1.0000x reference)
//
#include <hip/hip_runtime.h>
#include <math.h>

#define N_LOC 32768
#define CONTENT 512
#define ADDR_D 64
#define HID 1024
#define IN_D 256
#define OUT_D 10
#define OVERALL 576
#define GRU_IN 832
#define EPS_C 1e-7f
#define NSTEPS 8

#define NBLK_P 2048
#define NWAVE_P (NBLK_P * 4)     // 8192 waves; 4 rows/wave, all loads hoisted
#define RCOLS (OVERALL + 1)      // 576 reading cols + 1 ssum col
#define RP 580                   // padded LDS row length
#define RSP 580                  // padded rs-row length (per-step final reduced row)

__device__ __forceinline__ float wred(float v) {
    #pragma unroll
    for (int m = 32; m; m >>= 1) v += __shfl_xor(v, m, 64);
    return v;
}
__device__ __forceinline__ float sigm(float x) { return 1.0f / (1.0f + expf(-x)); }
__device__ __forceinline__ float dot4(float4 a, float4 b) {
    return a.x * b.x + a.y * b.y + a.z * b.z + a.w * b.w;
}
#define UPD(m, e, c, wv) \
    m.x = m.x * (1.0f - wv * e.x) + wv * c.x; \
    m.y = m.y * (1.0f - wv * e.y) + wv * c.y; \
    m.z = m.z * (1.0f - wv * e.z) + wv * c.z; \
    m.w = m.w * (1.0f - wv * e.w) + wv * c.w;

// ---------------- init: addr row norms^2, zero ema ----------------
__global__ __launch_bounds__(256) void k_init(const float* __restrict__ addrRows,
                                              float* __restrict__ addrsq,
                                              float* __restrict__ ema) {
    int tid = threadIdx.x, wid = tid >> 6, lane = tid & 63;
    int gid = blockIdx.x * 256 + tid;
    if (gid < N_LOC) ema[gid] = 0.0f;
    for (int i = blockIdx.x * 4 + wid; i < N_LOC; i += gridDim.x * 4) {
        float a = addrRows[(size_t)i * ADDR_D + lane];
        float sq = wred(a * a);
        if (lane == 0) addrsq[i] = sq;
    }
}

// ---------------- precompute (once): gix = W_ih[:, :256] @ x ; cix = W_ci @ x ;
// last block zeroes the rs accumulators (atomic targets) ----------------
__global__ __launch_bounds__(64) void k_pre(const float* __restrict__ W_ih,
                                            const float* __restrict__ W_ci,
                                            const float* __restrict__ x,
                                            float* __restrict__ gix,
                                            float* __restrict__ cix,
                                            float* __restrict__ rsAll) {
    int tid = threadIdx.x;
    int r = blockIdx.x;
    if (r == 3 * HID + CONTENT) {                 // zero rs accumulators
        for (int i = tid; i < NSTEPS * RSP; i += 64) rsAll[i] = 0.0f;
        return;
    }
    const float4* x4 = (const float4*)x;
    const float4* row;
    if (r < 3 * HID) row = (const float4*)(W_ih + (size_t)r * GRU_IN);
    else             row = (const float4*)(W_ci + (size_t)(r - 3 * HID) * IN_D);
    float d = dot4(row[tid], x4[tid]);            // IN_D = 256 = 64 float4s
    d = wred(d);
    if (tid == 0) {
        if (r < 3 * HID) gix[r] = d;
        else             cix[r - 3 * HID] = d;
    }
}

// ---------------- small matvecs: one output row per block, 256-thread K-split ----------------
// roles: 0=erase, 1=cand (uses precomputed cix), 2=query, 3=u_s.h, 4=u_l.h
__global__ __launch_bounds__(256) void k_small(
    const float* __restrict__ W_e, const float* __restrict__ b_e,
    const float* __restrict__ W_ch, const float* __restrict__ cix, const float* __restrict__ b_c,
    const float* __restrict__ W_q, const float* __restrict__ b_q,
    const float* __restrict__ u_s, const float* __restrict__ u_l,
    const float* __restrict__ h,
    float* __restrict__ erase, float* __restrict__ cand, float* __restrict__ query,
    float* __restrict__ slots_t, int doEC) {
    int tid = threadIdx.x, wid = tid >> 6, lane = tid & 63;
    int r = blockIdx.x;
    __shared__ float red[4];

    int role, rr;
    if (doEC) {
        if (r < CONTENT)                { role = 0; rr = r; }
        else if (r < 2 * CONTENT)       { role = 1; rr = r - CONTENT; }
        else if (r < 2 * CONTENT + OVERALL) { role = 2; rr = r - 2 * CONTENT; }
        else                            { role = 3 + (r - (2 * CONTENT + OVERALL)); rr = 0; }
    } else {
        if (r < OVERALL)                { role = 2; rr = r; }
        else                            { role = 3 + (r - OVERALL); rr = 0; }
    }

    const float4* h4 = (const float4*)h;
    const float4* row4;
    if (role == 0)      row4 = (const float4*)(W_e  + (size_t)rr * HID);
    else if (role == 1) row4 = (const float4*)(W_ch + (size_t)rr * HID);
    else if (role == 2) row4 = (const float4*)(W_q  + (size_t)rr * HID);
    else if (role == 3) row4 = (const float4*)u_s;
    else                row4 = (const float4*)u_l;

    float d = dot4(row4[tid], h4[tid]);     // HID = 256 float4s, one per thread
    d = wred(d);
    if (lane == 0) red[wid] = d;
    __syncthreads();
    if (tid == 0) {
        float s = red[0] + red[1] + red[2] + red[3];
        if (role == 0)      erase[rr] = sigm(s + b_e[rr]);
        else if (role == 1) cand[rr]  = fmaxf(s + cix[rr] + b_c[rr], 0.0f);
        else if (role == 2) query[rr] = s + b_q[rr];
        else if (role == 3) slots_t[1] = s;
        else                slots_t[2] = s;
    }
}

// ---------------- fused pass: full-lazy update replay + dots + sim + exp + reading
// numerators accumulated DIRECTLY into rs_t via fp32 atomics (no part buffer, no k_redf).
// mem is NEVER written: pass t rebuilds mem_t in registers from read-only memC by replaying
// updates u=0..t-1. NO __threadfence anywhere (r1 lesson: fence = L2 wb/inv storm, 13x).
// atomicAdd is fence-free and device-scope by default on CDNA4.
__global__ __launch_bounds__(256) void k_passAB(
    const float* __restrict__ memC,
    const float* __restrict__ addrRows, const float* __restrict__ query,
    const float* __restrict__ eraseAll, const float* __restrict__ candAll,
    const float* __restrict__ addrsq, float* __restrict__ ema,
    const float* __restrict__ expAll, float* __restrict__ exp_t,
    float* __restrict__ rs_t, const float* __restrict__ rsAll,
    const float* __restrict__ slots_t,
    const float* __restrict__ b_sh, const float* __restrict__ b_lr,
    int tstep) {
    int tid = threadIdx.x, wid = tid >> 6, lane = tid & 63;
    int gw = blockIdx.x * 4 + wid;
    const int i0 = gw;
    const int i1 = gw + NWAVE_P;
    const int i2 = gw + 2 * NWAVE_P;
    const int i3 = gw + 3 * NWAVE_P;

    __shared__ __align__(16) float lredw[4][RP];  // wave-private partial rows

    // ---- hoist ALL global loads (4 mem rows = 9KB/wave in flight) ----
    const float4* r0p = (const float4*)(memC + (size_t)i0 * CONTENT);
    const float4* r1p = (const float4*)(memC + (size_t)i1 * CONTENT);
    const float4* r2p = (const float4*)(memC + (size_t)i2 * CONTENT);
    const float4* r3p = (const float4*)(memC + (size_t)i3 * CONTENT);
    float4 m00 = r0p[lane], m01 = r0p[64 + lane];
    float4 m10 = r1p[lane], m11 = r1p[64 + lane];
    float4 m20 = r2p[lane], m21 = r2p[64 + lane];
    float4 m30 = r3p[lane], m31 = r3p[64 + lane];
    float av0 = addrRows[(size_t)i0 * ADDR_D + lane];
    float av1 = addrRows[(size_t)i1 * ADDR_D + lane];
    float av2 = addrRows[(size_t)i2 * ADDR_D + lane];
    float av3 = addrRows[(size_t)i3 * ADDR_D + lane];
    float eo0 = ema[i0], eo1 = ema[i1], eo2 = ema[i2], eo3 = ema[i3];
    float asq0 = addrsq[i0], asq1 = addrsq[i1], asq2 = addrsq[i2], asq3 = addrsq[i3];

    const float4 q0 = *(const float4*)(query + 4 * lane);
    const float4 q1 = *(const float4*)(query + 256 + 4 * lane);
    const float qa = query[512 + lane];
    const float qq = wred(dot4(q0, q0) + dot4(q1, q1) + qa * qa);
    const float qnorm = sqrtf(qq);
    const float bs = slots_t[1] + b_sh[0];
    const float beta = (bs > 20.0f ? bs : log1pf(expf(bs))) + 1.0f;
    const float gamma = sigm(slots_t[2] + b_lr[0]);

    // ---- replay updates u = 0 .. tstep-1 on registers ----
    for (int u = 0; u < tstep; u++) {
        const float4 e0 = *(const float4*)(eraseAll + (size_t)u * CONTENT + 4 * lane);
        const float4 e1 = *(const float4*)(eraseAll + (size_t)u * CONTENT + 256 + 4 * lane);
        const float4 c0 = *(const float4*)(candAll + (size_t)u * CONTENT + 4 * lane);
        const float4 c1 = *(const float4*)(candAll + (size_t)u * CONTENT + 256 + 4 * lane);
        const float invp = 1.0f / rsAll[(size_t)u * RSP + OVERALL];  // ssum of step u
        const float* eb = expAll + (size_t)u * N_LOC;
        const float wv0 = eb[i0] * invp;
        const float wv1 = eb[i1] * invp;
        const float wv2 = eb[i2] * invp;
        const float wv3 = eb[i3] * invp;
        UPD(m00, e0, c0, wv0) UPD(m01, e1, c1, wv0)
        UPD(m10, e0, c0, wv1) UPD(m11, e1, c1, wv1)
        UPD(m20, e0, c0, wv2) UPD(m21, e1, c1, wv2)
        UPD(m30, e0, c0, wv3) UPD(m31, e1, c1, wv3)
    }

    // ---- dots + norms: 8 interleaved reduction chains ----
    float d0 = dot4(m00, q0) + dot4(m01, q1) + av0 * qa;
    float d1 = dot4(m10, q0) + dot4(m11, q1) + av1 * qa;
    float d2 = dot4(m20, q0) + dot4(m21, q1) + av2 * qa;
    float d3 = dot4(m30, q0) + dot4(m31, q1) + av3 * qa;
    float s0 = dot4(m00, m00) + dot4(m01, m01);
    float s1 = dot4(m10, m10) + dot4(m11, m11);
    float s2 = dot4(m20, m20) + dot4(m21, m21);
    float s3 = dot4(m30, m30) + dot4(m31, m31);
    #pragma unroll
    for (int m = 32; m; m >>= 1) {
        d0 += __shfl_xor(d0, m, 64); s0 += __shfl_xor(s0, m, 64);
        d1 += __shfl_xor(d1, m, 64); s1 += __shfl_xor(s1, m, 64);
        d2 += __shfl_xor(d2, m, 64); s2 += __shfl_xor(s2, m, 64);
        d3 += __shfl_xor(d3, m, 64); s3 += __shfl_xor(s3, m, 64);
    }
    float sim0 = beta * d0 / (sqrtf(s0 + asq0) * qnorm + EPS_C);
    float sim1 = beta * d1 / (sqrtf(s1 + asq1) * qnorm + EPS_C);
    float sim2 = beta * d2 / (sqrtf(s2 + asq2) * qnorm + EPS_C);
    float sim3 = beta * d3 / (sqrtf(s3 + asq3) * qnorm + EPS_C);
    float es0 = expf(sim0 - gamma * eo0);
    float es1 = expf(sim1 - gamma * eo1);
    float es2 = expf(sim2 - gamma * eo2);
    float es3 = expf(sim3 - gamma * eo3);
    if (lane == 0) {
        ema[i0] = 0.1f * eo0 + 0.9f * sim0;
        ema[i1] = 0.1f * eo1 + 0.9f * sim1;
        ema[i2] = 0.1f * eo2 + 0.9f * sim2;
        ema[i3] = 0.1f * eo3 + 0.9f * sim3;
        exp_t[i0] = es0; exp_t[i1] = es1; exp_t[i2] = es2; exp_t[i3] = es3;
    }

    // ---- wave-private reading numerator rows (vectorized LDS stores) ----
    float* lw = lredw[wid];
    float4 va = make_float4(
        es0 * m00.x + es1 * m10.x + es2 * m20.x + es3 * m30.x,
        es0 * m00.y + es1 * m10.y + es2 * m20.y + es3 * m30.y,
        es0 * m00.z + es1 * m10.z + es2 * m20.z + es3 * m30.z,
        es0 * m00.w + es1 * m10.w + es2 * m20.w + es3 * m30.w);
    *(float4*)(lw + 4 * lane) = va;
    float4 vb = make_float4(
        es0 * m01.x + es1 * m11.x + es2 * m21.x + es3 * m31.x,
        es0 * m01.y + es1 * m11.y + es2 * m21.y + es3 * m31.y,
        es0 * m01.z + es1 * m11.z + es2 * m21.z + es3 * m31.z,
        es0 * m01.w + es1 * m11.w + es2 * m21.w + es3 * m31.w);
    *(float4*)(lw + 256 + 4 * lane) = vb;
    lw[512 + lane] = es0 * av0 + es1 * av1 + es2 * av2 + es3 * av3;
    if (lane == 0) lw[576] = es0 + es1 + es2 + es3;   // es are wave-uniform
    __syncthreads();

    // ---- combine 4 wave rows, accumulate straight into rs_t (fence-free atomics) ----
    for (int c = tid; c < RCOLS; c += 256) {
        float v = lredw[0][c] + lredw[1][c] + lredw[2][c] + lredw[3][c];
        atomicAdd(&rs_t[c], v);
    }
}

// ---------------- GRU: one hidden unit per block, K-split over reading + h ----------------
__global__ __launch_bounds__(256) void k_gru(
    const float* __restrict__ W_ih, const float* __restrict__ W_hh,
    const float* __restrict__ b_ih, const float* __restrict__ b_hh,
    const float* __restrict__ gix, const float* __restrict__ rs,
    const float* __restrict__ hcur, float* __restrict__ hnew) {
    int tid = threadIdx.x, wid = tid >> 6, lane = tid & 63;
    const int k = blockIdx.x;
    __shared__ float red[4][6];

    const float invs = 1.0f / rs[OVERALL];   // ssum
    const float4* Wi0 = (const float4*)(W_ih + (size_t)k * GRU_IN + IN_D);
    const float4* Wi1 = (const float4*)(W_ih + (size_t)(k + HID) * GRU_IN + IN_D);
    const float4* Wi2 = (const float4*)(W_ih + (size_t)(k + 2 * HID) * GRU_IN + IN_D);
    const float4* Wh0 = (const float4*)(W_hh + (size_t)k * HID);
    const float4* Wh1 = (const float4*)(W_hh + (size_t)(k + HID) * HID);
    const float4* Wh2 = (const float4*)(W_hh + (size_t)(k + 2 * HID) * HID);

    float gi0 = 0, gi1 = 0, gi2 = 0;
    if (tid < OVERALL / 4) {            // 144 float4s of reading
        float4 v = ((const float4*)rs)[tid];
        v.x *= invs; v.y *= invs; v.z *= invs; v.w *= invs;
        gi0 = dot4(Wi0[tid], v); gi1 = dot4(Wi1[tid], v); gi2 = dot4(Wi2[tid], v);
    }
    float4 hv = ((const float4*)hcur)[tid];  // HID = 256 float4s
    float gh0 = dot4(Wh0[tid], hv);
    float gh1 = dot4(Wh1[tid], hv);
    float gh2 = dot4(Wh2[tid], hv);

    #pragma unroll
    for (int m = 32; m; m >>= 1) {
        gi0 += __shfl_xor(gi0, m, 64); gi1 += __shfl_xor(gi1, m, 64); gi2 += __shfl_xor(gi2, m, 64);
        gh0 += __shfl_xor(gh0, m, 64); gh1 += __shfl_xor(gh1, m, 64); gh2 += __shfl_xor(gh2, m, 64);
    }
    if (lane == 0) {
        red[wid][0] = gi0; red[wid][1] = gi1; red[wid][2] = gi2;
        red[wid][3] = gh0; red[wid][4] = gh1; red[wid][5] = gh2;
    }
    __syncthreads();
    if (tid == 0) {
        float a0 = red[0][0] + red[1][0] + red[2][0] + red[3][0] + gix[k];
        float a1 = red[0][1] + red[1][1] + red[2][1] + red[3][1] + gix[HID + k];
        float a2 = red[0][2] + red[1][2] + red[2][2] + red[3][2] + gix[2 * HID + k];
        float a3 = red[0][3] + red[1][3] + red[2][3] + red[3][3];
        float a4 = red[0][4] + red[1][4] + red[2][4] + red[3][4];
        float a5 = red[0][5] + red[1][5] + red[2][5] + red[3][5];
        float r = sigm(a0 + b_ih[k] + a3 + b_hh[k]);
        float z = sigm(a1 + b_ih[HID + k] + a4 + b_hh[HID + k]);
        float n = tanhf(a2 + b_ih[2 * HID + k] + r * (a5 + b_hh[2 * HID + k]));
        hnew[k] = (1.0f - z) * n + z * hcur[k];
    }
}

// ---------------- output: copy h, logits + log_softmax ----------------
__global__ __launch_bounds__(256) void k_out(const float* __restrict__ W_o,
                                             const float* __restrict__ b_o,
                                             const float* __restrict__ h,
                                             float* __restrict__ out) {
    int tid = threadIdx.x, wid = tid >> 6, lane = tid & 63;
    __shared__ float lg[OUT_D];
    for (int j = tid; j < HID; j += 256) out[j] = h[j];
    const float4* h4 = (const float4*)h;
    for (int u = wid; u < OUT_D; u += 4) {
        const float4* row = (const float4*)(W_o + (size_t)u * HID);
        float d = 0.0f;
        #pragma unroll
        for (int i = 0; i < 4; i++) d += dot4(row[lane + 64 * i], h4[lane + 64 * i]);
        d = wred(d);
        if (lane == 0) lg[u] = d + b_o[u];
    }
    __syncthreads();
    if (tid == 0) {
        float m = -1e30f;
        for (int u = 0; u < OUT_D; u++) m = fmaxf(m, lg[u]);
        float se = 0.0f;
        for (int u = 0; u < OUT_D; u++) se += expf(lg[u] - m);
        float lse = m + logf(se);
        for (int u = 0; u < OUT_D; u++) out[HID + u] = lg[u] - lse;
    }
}

extern "C" void kernel_launch(void* const* d_in, const int* in_sizes, int n_in,
                              void* d_out, int out_size, void* d_ws, size_t ws_size,
                              hipStream_t stream) {
    const float* x    = (const float*)d_in[0];
    const float* h0   = (const float*)d_in[1];
    const float* memC = (const float*)d_in[2];
    const float* addrR= (const float*)d_in[3];
    const float* W_q  = (const float*)d_in[4];
    const float* b_q  = (const float*)d_in[5];
    const float* u_s  = (const float*)d_in[6];
    const float* b_s  = (const float*)d_in[7];
    const float* u_l  = (const float*)d_in[8];
    const float* b_l  = (const float*)d_in[9];
    const float* W_e  = (const float*)d_in[10];
    const float* b_e  = (const float*)d_in[11];
    const float* W_ch = (const float*)d_in[12];
    const float* W_ci = (const float*)d_in[13];
    const float* b_c  = (const float*)d_in[14];
    const float* W_ih = (const float*)d_in[15];
    const float* W_hh = (const float*)d_in[16];
    const float* b_ih = (const float*)d_in[17];
    const float* b_hh = (const float*)d_in[18];
    const float* W_o  = (const float*)d_in[19];
    const float* b_o  = (const float*)d_in[20];

    // workspace layout (floats) — no mem buffer, no part buffer
    const size_t SM_ADDRSQ = 0;
    const size_t SM_EXPA   = SM_ADDRSQ + N_LOC;                  // NSTEPS * N_LOC
    const size_t SM_EMA    = SM_EXPA + (size_t)NSTEPS * N_LOC;
    const size_t SM_QUERY  = SM_EMA + N_LOC;
    const size_t SM_ER     = SM_QUERY + NSTEPS * OVERALL;
    const size_t SM_CAND   = SM_ER + NSTEPS * CONTENT;
    const size_t SM_H      = SM_CAND + NSTEPS * CONTENT;
    const size_t SM_SLOTS  = SM_H + (NSTEPS + 1) * HID;
    const size_t SM_RS     = SM_SLOTS + NSTEPS * 8;              // NSTEPS * RSP
    const size_t SM_GIX    = SM_RS + (size_t)NSTEPS * RSP;       // 3*HID
    const size_t SM_CIX    = SM_GIX + 3 * HID;                   // CONTENT

    float* sb = (float*)d_ws;
    float* addrsq  = sb + SM_ADDRSQ;
    float* exp_all = sb + SM_EXPA;
    float* ema     = sb + SM_EMA;
    float* query   = sb + SM_QUERY;
    float* erase   = sb + SM_ER;
    float* cand    = sb + SM_CAND;
    float* H       = sb + SM_H;
    float* slots   = sb + SM_SLOTS;
    float* rsAll   = sb + SM_RS;
    float* gix     = sb + SM_GIX;
    float* cix     = sb + SM_CIX;

    k_init<<<512, 256, 0, stream>>>(addrR, addrsq, ema);
    k_pre<<<3 * HID + CONTENT + 1, 64, 0, stream>>>(W_ih, W_ci, x, gix, cix, rsAll);
    k_small<<<OVERALL + 2, 256, 0, stream>>>(
        W_e, b_e, W_ch, cix, b_c, W_q, b_q, u_s, u_l, h0,
        erase, cand, query, slots, 0);

    const float* hcur = h0;
    for (int t = 0; t < NSTEPS; t++) {
        float* rs_t = rsAll + (size_t)t * RSP;
        k_passAB<<<NBLK_P, 256, 0, stream>>>(
            memC, addrR,
            query + t * OVERALL,
            erase, cand,
            addrsq, ema,
            exp_all, exp_all + (size_t)t * N_LOC,
            rs_t, rsAll,
            slots + t * 8, b_s, b_l,
            t);
        float* hn = H + (t + 1) * HID;
        k_gru<<<HID, 256, 0, stream>>>(W_ih, W_hh, b_ih, b_hh, gix,
                                       rs_t, hcur, hn);
        if (t < NSTEPS - 1) {
            k_small<<<2 * CONTENT + OVERALL + 2, 256, 0, stream>>>(
                W_e, b_e, W_ch, cix, b_c, W_q, b_q, u_s, u_l, hn,
                erase + t * CONTENT, cand + t * CONTENT,
                query + (t + 1) * OVERALL, slots + (t + 1) * 8, 1);
        }
        hcur = hn;
    }
    k_out<<<1, 256, 0, stream>>>(W_o, b_o, hcur, (float*)d_out);
}

// Round 7
// 576.012 us; speedup vs baseline: 1.4059x; 1.4059x over previous
//
#include <hip/hip_runtime.h>
#include <math.h>

#define N_LOC 32768
#define CONTENT 512
#define ADDR_D 64
#define HID 1024
#define IN_D 256
#define OUT_D 10
#define OVERALL 576
#define GRU_IN 832
#define EPS_C 1e-7f
#define NSTEPS 8

#define NBLK_P 1024              // 8 rows/wave now: 4096 waves x 8 rows = 32768
#define NWAVE_P (NBLK_P * 4)
#define RPW 8                    // rows per wave
#define RCOLS (OVERALL + 1)      // 576 reading cols + 1 ssum col
#define RP 580                   // padded part-row length (16B-aligned rows)
#define RSP 580                  // padded rs-row length

__device__ __forceinline__ float wred(float v) {
    #pragma unroll
    for (int m = 32; m; m >>= 1) v += __shfl_xor(v, m, 64);
    return v;
}
__device__ __forceinline__ float sigm(float x) { return 1.0f / (1.0f + expf(-x)); }
__device__ __forceinline__ float dot4(float4 a, float4 b) {
    return a.x * b.x + a.y * b.y + a.z * b.z + a.w * b.w;
}
#define UPD(m, e, c, wv) \
    m.x = m.x * (1.0f - wv * e.x) + wv * c.x; \
    m.y = m.y * (1.0f - wv * e.y) + wv * c.y; \
    m.z = m.z * (1.0f - wv * e.z) + wv * c.z; \
    m.w = m.w * (1.0f - wv * e.w) + wv * c.w;

// ---------------- init: addr row norms^2, zero ema ----------------
__global__ __launch_bounds__(256) void k_init(const float* __restrict__ addrRows,
                                              float* __restrict__ addrsq,
                                              float* __restrict__ ema) {
    int tid = threadIdx.x, wid = tid >> 6, lane = tid & 63;
    int gid = blockIdx.x * 256 + tid;
    if (gid < N_LOC) ema[gid] = 0.0f;
    for (int i = blockIdx.x * 4 + wid; i < N_LOC; i += gridDim.x * 4) {
        float a = addrRows[(size_t)i * ADDR_D + lane];
        float sq = wred(a * a);
        if (lane == 0) addrsq[i] = sq;
    }
}

// ---------------- precompute (once): gix = W_ih[:, :256] @ x ; cix = W_ci @ x ----------------
__global__ __launch_bounds__(64) void k_pre(const float* __restrict__ W_ih,
                                            const float* __restrict__ W_ci,
                                            const float* __restrict__ x,
                                            float* __restrict__ gix,
                                            float* __restrict__ cix) {
    int tid = threadIdx.x;
    int r = blockIdx.x;
    const float4* x4 = (const float4*)x;
    const float4* row;
    if (r < 3 * HID) row = (const float4*)(W_ih + (size_t)r * GRU_IN);
    else             row = (const float4*)(W_ci + (size_t)(r - 3 * HID) * IN_D);
    float d = dot4(row[tid], x4[tid]);
    d = wred(d);
    if (tid == 0) {
        if (r < 3 * HID) gix[r] = d;
        else             cix[r - 3 * HID] = d;
    }
}

// ---------------- small matvecs: one output row per block, 256-thread K-split ----------------
__global__ __launch_bounds__(256) void k_small(
    const float* __restrict__ W_e, const float* __restrict__ b_e,
    const float* __restrict__ W_ch, const float* __restrict__ cix, const float* __restrict__ b_c,
    const float* __restrict__ W_q, const float* __restrict__ b_q,
    const float* __restrict__ u_s, const float* __restrict__ u_l,
    const float* __restrict__ h,
    float* __restrict__ erase, float* __restrict__ cand, float* __restrict__ query,
    float* __restrict__ slots_t, int doEC) {
    int tid = threadIdx.x, wid = tid >> 6, lane = tid & 63;
    int r = blockIdx.x;
    __shared__ float red[4];

    int role, rr;
    if (doEC) {
        if (r < CONTENT)                { role = 0; rr = r; }
        else if (r < 2 * CONTENT)       { role = 1; rr = r - CONTENT; }
        else if (r < 2 * CONTENT + OVERALL) { role = 2; rr = r - 2 * CONTENT; }
        else                            { role = 3 + (r - (2 * CONTENT + OVERALL)); rr = 0; }
    } else {
        if (r < OVERALL)                { role = 2; rr = r; }
        else                            { role = 3 + (r - OVERALL); rr = 0; }
    }

    const float4* h4 = (const float4*)h;
    const float4* row4;
    if (role == 0)      row4 = (const float4*)(W_e  + (size_t)rr * HID);
    else if (role == 1) row4 = (const float4*)(W_ch + (size_t)rr * HID);
    else if (role == 2) row4 = (const float4*)(W_q  + (size_t)rr * HID);
    else if (role == 3) row4 = (const float4*)u_s;
    else                row4 = (const float4*)u_l;

    float d = dot4(row4[tid], h4[tid]);
    d = wred(d);
    if (lane == 0) red[wid] = d;
    __syncthreads();
    if (tid == 0) {
        float s = red[0] + red[1] + red[2] + red[3];
        if (role == 0)      erase[rr] = sigm(s + b_e[rr]);
        else if (role == 1) cand[rr]  = fmaxf(s + cix[rr] + b_c[rr], 0.0f);
        else if (role == 2) query[rr] = s + b_q[rr];
        else if (role == 3) slots_t[1] = s;
        else                slots_t[2] = s;
    }
}

// ---------------- fused pass: lazy replay + dots + sim + exp + reading partials ----------------
// 8 rows/wave (2x r4): doubles in-flight loads & shfl ILP, halves per-row fixed overhead.
// mem NEVER written; part+k_redf reduction (r1: fences catastrophic; r6: narrow atomics
// serialize on 9 cachelines ~50us — coalesced part stores + kernel boundary is the way).
__global__ __launch_bounds__(256) void k_passAB(
    const float* __restrict__ memC,
    const float* __restrict__ addrRows, const float* __restrict__ query,
    const float* __restrict__ eraseAll, const float* __restrict__ candAll,
    const float* __restrict__ addrsq, float* __restrict__ ema,
    const float* __restrict__ expAll, float* __restrict__ exp_t,
    float* __restrict__ part, const float* __restrict__ rsAll,
    const float* __restrict__ slots_t,
    const float* __restrict__ b_sh, const float* __restrict__ b_lr,
    int tstep) {
    int tid = threadIdx.x, wid = tid >> 6, lane = tid & 63;
    int gw = blockIdx.x * 4 + wid;

    __shared__ __align__(16) float lredw[4][RP];  // wave-private partial rows

    // ---- hoist ALL global loads (8 mem rows = 18KB/wave in flight) ----
    float4 m[RPW][2];
    float av[RPW], eo[RPW], asq[RPW];
    #pragma unroll
    for (int r = 0; r < RPW; r++) {
        int i = gw + r * NWAVE_P;
        const float4* rp = (const float4*)(memC + (size_t)i * CONTENT);
        m[r][0] = rp[lane]; m[r][1] = rp[64 + lane];
        av[r] = addrRows[(size_t)i * ADDR_D + lane];
        eo[r] = ema[i];
        asq[r] = addrsq[i];
    }

    const float4 q0 = *(const float4*)(query + 4 * lane);
    const float4 q1 = *(const float4*)(query + 256 + 4 * lane);
    const float qa = query[512 + lane];
    const float qq = wred(dot4(q0, q0) + dot4(q1, q1) + qa * qa);
    const float qnorm = sqrtf(qq);
    const float bs = slots_t[1] + b_sh[0];
    const float beta = (bs > 20.0f ? bs : log1pf(expf(bs))) + 1.0f;
    const float gamma = sigm(slots_t[2] + b_lr[0]);

    // ---- replay updates u = 0 .. tstep-1 on registers (identical op order -> bit-exact) ----
    for (int u = 0; u < tstep; u++) {
        const float4 e0 = *(const float4*)(eraseAll + (size_t)u * CONTENT + 4 * lane);
        const float4 e1 = *(const float4*)(eraseAll + (size_t)u * CONTENT + 256 + 4 * lane);
        const float4 c0 = *(const float4*)(candAll + (size_t)u * CONTENT + 4 * lane);
        const float4 c1 = *(const float4*)(candAll + (size_t)u * CONTENT + 256 + 4 * lane);
        const float invp = 1.0f / rsAll[(size_t)u * RSP + OVERALL];  // ssum of step u
        const float* eb = expAll + (size_t)u * N_LOC;
        #pragma unroll
        for (int r = 0; r < RPW; r++) {
            float wv = eb[gw + r * NWAVE_P] * invp;
            UPD(m[r][0], e0, c0, wv)
            UPD(m[r][1], e1, c1, wv)
        }
    }

    // ---- dots + norms: two groups of 4 rows, 8 interleaved chains each ----
    float es[RPW];
    #pragma unroll
    for (int g = 0; g < 2; g++) {
        float d0 = dot4(m[4*g+0][0], q0) + dot4(m[4*g+0][1], q1) + av[4*g+0] * qa;
        float d1 = dot4(m[4*g+1][0], q0) + dot4(m[4*g+1][1], q1) + av[4*g+1] * qa;
        float d2 = dot4(m[4*g+2][0], q0) + dot4(m[4*g+2][1], q1) + av[4*g+2] * qa;
        float d3 = dot4(m[4*g+3][0], q0) + dot4(m[4*g+3][1], q1) + av[4*g+3] * qa;
        float s0 = dot4(m[4*g+0][0], m[4*g+0][0]) + dot4(m[4*g+0][1], m[4*g+0][1]);
        float s1 = dot4(m[4*g+1][0], m[4*g+1][0]) + dot4(m[4*g+1][1], m[4*g+1][1]);
        float s2 = dot4(m[4*g+2][0], m[4*g+2][0]) + dot4(m[4*g+2][1], m[4*g+2][1]);
        float s3 = dot4(m[4*g+3][0], m[4*g+3][0]) + dot4(m[4*g+3][1], m[4*g+3][1]);
        #pragma unroll
        for (int mm = 32; mm; mm >>= 1) {
            d0 += __shfl_xor(d0, mm, 64); s0 += __shfl_xor(s0, mm, 64);
            d1 += __shfl_xor(d1, mm, 64); s1 += __shfl_xor(s1, mm, 64);
            d2 += __shfl_xor(d2, mm, 64); s2 += __shfl_xor(s2, mm, 64);
            d3 += __shfl_xor(d3, mm, 64); s3 += __shfl_xor(s3, mm, 64);
        }
        float sim0 = beta * d0 / (sqrtf(s0 + asq[4*g+0]) * qnorm + EPS_C);
        float sim1 = beta * d1 / (sqrtf(s1 + asq[4*g+1]) * qnorm + EPS_C);
        float sim2 = beta * d2 / (sqrtf(s2 + asq[4*g+2]) * qnorm + EPS_C);
        float sim3 = beta * d3 / (sqrtf(s3 + asq[4*g+3]) * qnorm + EPS_C);
        es[4*g+0] = expf(sim0 - gamma * eo[4*g+0]);
        es[4*g+1] = expf(sim1 - gamma * eo[4*g+1]);
        es[4*g+2] = expf(sim2 - gamma * eo[4*g+2]);
        es[4*g+3] = expf(sim3 - gamma * eo[4*g+3]);
        eo[4*g+0] = 0.1f * eo[4*g+0] + 0.9f * sim0;
        eo[4*g+1] = 0.1f * eo[4*g+1] + 0.9f * sim1;
        eo[4*g+2] = 0.1f * eo[4*g+2] + 0.9f * sim2;
        eo[4*g+3] = 0.1f * eo[4*g+3] + 0.9f * sim3;
    }
    if (lane == 0) {
        #pragma unroll
        for (int r = 0; r < RPW; r++) {
            int i = gw + r * NWAVE_P;
            ema[i] = eo[r];
            exp_t[i] = es[r];
        }
    }

    // ---- wave-private reading numerator rows (vectorized LDS stores) ----
    {
        float ax = 0, ay = 0, az = 0, aw = 0, px = 0, py = 0, pz = 0, pw = 0, avs = 0, ess = 0;
        #pragma unroll
        for (int r = 0; r < RPW; r++) {
            ax += es[r] * m[r][0].x; ay += es[r] * m[r][0].y;
            az += es[r] * m[r][0].z; aw += es[r] * m[r][0].w;
            px += es[r] * m[r][1].x; py += es[r] * m[r][1].y;
            pz += es[r] * m[r][1].z; pw += es[r] * m[r][1].w;
            avs += es[r] * av[r]; ess += es[r];
        }
        float* lw = lredw[wid];
        *(float4*)(lw + 4 * lane) = make_float4(ax, ay, az, aw);
        *(float4*)(lw + 256 + 4 * lane) = make_float4(px, py, pz, pw);
        lw[512 + lane] = avs;
        if (lane == 0) lw[576] = ess;
    }
    __syncthreads();

    // ---- combine 4 wave rows, store coalesced into part[b][c] ----
    float* pb = part + (size_t)blockIdx.x * RP;
    for (int c = tid; c < RCOLS; c += 256)
        pb[c] = lredw[0][c] + lredw[1][c] + lredw[2][c] + lredw[3][c];
}

// ---------------- final reduce: one column per block over all 1024 part rows ----------------
__global__ __launch_bounds__(256) void k_redf(const float* __restrict__ part,
                                              float* __restrict__ rs) {
    int tid = threadIdx.x, wid = tid >> 6, lane = tid & 63;
    int c = blockIdx.x;
    __shared__ float red[4];
    float acc = 0.0f;
    #pragma unroll
    for (int j = 0; j < NBLK_P / 256; j++)
        acc += part[(size_t)(tid + 256 * j) * RP + c];
    acc = wred(acc);
    if (lane == 0) red[wid] = acc;
    __syncthreads();
    if (tid == 0) rs[c] = red[0] + red[1] + red[2] + red[3];
}

// ---------------- GRU: one hidden unit per block, K-split over reading + h ----------------
__global__ __launch_bounds__(256) void k_gru(
    const float* __restrict__ W_ih, const float* __restrict__ W_hh,
    const float* __restrict__ b_ih, const float* __restrict__ b_hh,
    const float* __restrict__ gix, const float* __restrict__ rs,
    const float* __restrict__ hcur, float* __restrict__ hnew) {
    int tid = threadIdx.x, wid = tid >> 6, lane = tid & 63;
    const int k = blockIdx.x;
    __shared__ float red[4][6];

    const float invs = 1.0f / rs[OVERALL];   // ssum
    const float4* Wi0 = (const float4*)(W_ih + (size_t)k * GRU_IN + IN_D);
    const float4* Wi1 = (const float4*)(W_ih + (size_t)(k + HID) * GRU_IN + IN_D);
    const float4* Wi2 = (const float4*)(W_ih + (size_t)(k + 2 * HID) * GRU_IN + IN_D);
    const float4* Wh0 = (const float4*)(W_hh + (size_t)k * HID);
    const float4* Wh1 = (const float4*)(W_hh + (size_t)(k + HID) * HID);
    const float4* Wh2 = (const float4*)(W_hh + (size_t)(k + 2 * HID) * HID);

    float gi0 = 0, gi1 = 0, gi2 = 0;
    if (tid < OVERALL / 4) {            // 144 float4s of reading
        float4 v = ((const float4*)rs)[tid];
        v.x *= invs; v.y *= invs; v.z *= invs; v.w *= invs;
        gi0 = dot4(Wi0[tid], v); gi1 = dot4(Wi1[tid], v); gi2 = dot4(Wi2[tid], v);
    }
    float4 hv = ((const float4*)hcur)[tid];  // HID = 256 float4s
    float gh0 = dot4(Wh0[tid], hv);
    float gh1 = dot4(Wh1[tid], hv);
    float gh2 = dot4(Wh2[tid], hv);

    #pragma unroll
    for (int m = 32; m; m >>= 1) {
        gi0 += __shfl_xor(gi0, m, 64); gi1 += __shfl_xor(gi1, m, 64); gi2 += __shfl_xor(gi2, m, 64);
        gh0 += __shfl_xor(gh0, m, 64); gh1 += __shfl_xor(gh1, m, 64); gh2 += __shfl_xor(gh2, m, 64);
    }
    if (lane == 0) {
        red[wid][0] = gi0; red[wid][1] = gi1; red[wid][2] = gi2;
        red[wid][3] = gh0; red[wid][4] = gh1; red[wid][5] = gh2;
    }
    __syncthreads();
    if (tid == 0) {
        float a0 = red[0][0] + red[1][0] + red[2][0] + red[3][0] + gix[k];
        float a1 = red[0][1] + red[1][1] + red[2][1] + red[3][1] + gix[HID + k];
        float a2 = red[0][2] + red[1][2] + red[2][2] + red[3][2] + gix[2 * HID + k];
        float a3 = red[0][3] + red[1][3] + red[2][3] + red[3][3];
        float a4 = red[0][4] + red[1][4] + red[2][4] + red[3][4];
        float a5 = red[0][5] + red[1][5] + red[2][5] + red[3][5];
        float r = sigm(a0 + b_ih[k] + a3 + b_hh[k]);
        float z = sigm(a1 + b_ih[HID + k] + a4 + b_hh[HID + k]);
        float n = tanhf(a2 + b_ih[2 * HID + k] + r * (a5 + b_hh[2 * HID + k]));
        hnew[k] = (1.0f - z) * n + z * hcur[k];
    }
}

// ---------------- output: copy h, logits + log_softmax ----------------
__global__ __launch_bounds__(256) void k_out(const float* __restrict__ W_o,
                                             const float* __restrict__ b_o,
                                             const float* __restrict__ h,
                                             float* __restrict__ out) {
    int tid = threadIdx.x, wid = tid >> 6, lane = tid & 63;
    __shared__ float lg[OUT_D];
    for (int j = tid; j < HID; j += 256) out[j] = h[j];
    const float4* h4 = (const float4*)h;
    for (int u = wid; u < OUT_D; u += 4) {
        const float4* row = (const float4*)(W_o + (size_t)u * HID);
        float d = 0.0f;
        #pragma unroll
        for (int i = 0; i < 4; i++) d += dot4(row[lane + 64 * i], h4[lane + 64 * i]);
        d = wred(d);
        if (lane == 0) lg[u] = d + b_o[u];
    }
    __syncthreads();
    if (tid == 0) {
        float m = -1e30f;
        for (int u = 0; u < OUT_D; u++) m = fmaxf(m, lg[u]);
        float se = 0.0f;
        for (int u = 0; u < OUT_D; u++) se += expf(lg[u] - m);
        float lse = m + logf(se);
        for (int u = 0; u < OUT_D; u++) out[HID + u] = lg[u] - lse;
    }
}

extern "C" void kernel_launch(void* const* d_in, const int* in_sizes, int n_in,
                              void* d_out, int out_size, void* d_ws, size_t ws_size,
                              hipStream_t stream) {
    const float* x    = (const float*)d_in[0];
    const float* h0   = (const float*)d_in[1];
    const float* memC = (const float*)d_in[2];
    const float* addrR= (const float*)d_in[3];
    const float* W_q  = (const float*)d_in[4];
    const float* b_q  = (const float*)d_in[5];
    const float* u_s  = (const float*)d_in[6];
    const float* b_s  = (const float*)d_in[7];
    const float* u_l  = (const float*)d_in[8];
    const float* b_l  = (const float*)d_in[9];
    const float* W_e  = (const float*)d_in[10];
    const float* b_e  = (const float*)d_in[11];
    const float* W_ch = (const float*)d_in[12];
    const float* W_ci = (const float*)d_in[13];
    const float* b_c  = (const float*)d_in[14];
    const float* W_ih = (const float*)d_in[15];
    const float* W_hh = (const float*)d_in[16];
    const float* b_ih = (const float*)d_in[17];
    const float* b_hh = (const float*)d_in[18];
    const float* W_o  = (const float*)d_in[19];
    const float* b_o  = (const float*)d_in[20];

    // workspace layout (floats)
    const size_t SM_ADDRSQ = 0;
    const size_t SM_EXPA   = SM_ADDRSQ + N_LOC;                  // NSTEPS * N_LOC
    const size_t SM_EMA    = SM_EXPA + (size_t)NSTEPS * N_LOC;
    const size_t SM_QUERY  = SM_EMA + N_LOC;
    const size_t SM_ER     = SM_QUERY + NSTEPS * OVERALL;
    const size_t SM_CAND   = SM_ER + NSTEPS * CONTENT;
    const size_t SM_H      = SM_CAND + NSTEPS * CONTENT;
    const size_t SM_SLOTS  = SM_H + (NSTEPS + 1) * HID;
    const size_t SM_RS     = SM_SLOTS + NSTEPS * 8;              // NSTEPS * RSP
    const size_t SM_GIX    = SM_RS + (size_t)NSTEPS * RSP;       // 3*HID
    const size_t SM_CIX    = SM_GIX + 3 * HID;                   // CONTENT
    const size_t SM_PART   = SM_CIX + CONTENT;                   // NBLK_P * RP

    float* sb = (float*)d_ws;
    float* addrsq  = sb + SM_ADDRSQ;
    float* exp_all = sb + SM_EXPA;
    float* ema     = sb + SM_EMA;
    float* query   = sb + SM_QUERY;
    float* erase   = sb + SM_ER;
    float* cand    = sb + SM_CAND;
    float* H       = sb + SM_H;
    float* slots   = sb + SM_SLOTS;
    float* rsAll   = sb + SM_RS;
    float* gix     = sb + SM_GIX;
    float* cix     = sb + SM_CIX;
    float* part    = sb + SM_PART;

    k_init<<<512, 256, 0, stream>>>(addrR, addrsq, ema);
    k_pre<<<3 * HID + CONTENT, 64, 0, stream>>>(W_ih, W_ci, x, gix, cix);
    k_small<<<OVERALL + 2, 256, 0, stream>>>(
        W_e, b_e, W_ch, cix, b_c, W_q, b_q, u_s, u_l, h0,
        erase, cand, query, slots, 0);

    const float* hcur = h0;
    for (int t = 0; t < NSTEPS; t++) {
        k_passAB<<<NBLK_P, 256, 0, stream>>>(
            memC, addrR,
            query + t * OVERALL,
            erase, cand,
            addrsq, ema,
            exp_all, exp_all + (size_t)t * N_LOC,
            part, rsAll,
            slots + t * 8, b_s, b_l,
            t);
        float* rs_t = rsAll + (size_t)t * RSP;
        k_redf<<<RCOLS, 256, 0, stream>>>(part, rs_t);
        float* hn = H + (t + 1) * HID;
        k_gru<<<HID, 256, 0, stream>>>(W_ih, W_hh, b_ih, b_hh, gix,
                                       rs_t, hcur, hn);
        if (t < NSTEPS - 1) {
            k_small<<<2 * CONTENT + OVERALL + 2, 256, 0, stream>>>(
                W_e, b_e, W_ch, cix, b_c, W_q, b_q, u_s, u_l, hn,
                erase + t * CONTENT, cand + t * CONTENT,
                query + (t + 1) * OVERALL, slots + (t + 1) * 8, 1);
        }
        hcur = hn;
    }
    k_out<<<1, 256, 0, stream>>>(W_o, b_o, hcur, (float*)d_out);
}

// Round 8
// 516.542 us; speedup vs baseline: 1.5677x; 1.1151x over previous
//
#include <hip/hip_runtime.h>
#include <math.h>

#define N_LOC 32768
#define CONTENT 512
#define ADDR_D 64
#define HID 1024
#define IN_D 256
#define OUT_D 10
#define OVERALL 576
#define GRU_IN 832
#define EPS_C 1e-7f
#define NSTEPS 8

#define NBLK_P 1024              // 8 rows/wave: 4096 waves x 8 rows = 32768
#define NWAVE_P (NBLK_P * 4)
#define RPW 8                    // rows per wave, processed in 2 groups of 4
#define RCOLS (OVERALL + 1)      // 576 reading cols + 1 ssum col
#define RP 580                   // padded part-row length (16B-aligned rows)
#define RSP 580                  // padded rs-row length

__device__ __forceinline__ float wred(float v) {
    #pragma unroll
    for (int m = 32; m; m >>= 1) v += __shfl_xor(v, m, 64);
    return v;
}
__device__ __forceinline__ float sigm(float x) { return 1.0f / (1.0f + expf(-x)); }
__device__ __forceinline__ float dot4(float4 a, float4 b) {
    return a.x * b.x + a.y * b.y + a.z * b.z + a.w * b.w;
}
#define UPD(m, e, c, wv) \
    m.x = m.x * (1.0f - wv * e.x) + wv * c.x; \
    m.y = m.y * (1.0f - wv * e.y) + wv * c.y; \
    m.z = m.z * (1.0f - wv * e.z) + wv * c.z; \
    m.w = m.w * (1.0f - wv * e.w) + wv * c.w;

// ---------------- init: addr row norms^2, zero ema ----------------
__global__ __launch_bounds__(256) void k_init(const float* __restrict__ addrRows,
                                              float* __restrict__ addrsq,
                                              float* __restrict__ ema) {
    int tid = threadIdx.x, wid = tid >> 6, lane = tid & 63;
    int gid = blockIdx.x * 256 + tid;
    if (gid < N_LOC) ema[gid] = 0.0f;
    for (int i = blockIdx.x * 4 + wid; i < N_LOC; i += gridDim.x * 4) {
        float a = addrRows[(size_t)i * ADDR_D + lane];
        float sq = wred(a * a);
        if (lane == 0) addrsq[i] = sq;
    }
}

// ---------------- precompute (once): gix = W_ih[:, :256] @ x ; cix = W_ci @ x ----------------
__global__ __launch_bounds__(64) void k_pre(const float* __restrict__ W_ih,
                                            const float* __restrict__ W_ci,
                                            const float* __restrict__ x,
                                            float* __restrict__ gix,
                                            float* __restrict__ cix) {
    int tid = threadIdx.x;
    int r = blockIdx.x;
    const float4* x4 = (const float4*)x;
    const float4* row;
    if (r < 3 * HID) row = (const float4*)(W_ih + (size_t)r * GRU_IN);
    else             row = (const float4*)(W_ci + (size_t)(r - 3 * HID) * IN_D);
    float d = dot4(row[tid], x4[tid]);
    d = wred(d);
    if (tid == 0) {
        if (r < 3 * HID) gix[r] = d;
        else             cix[r - 3 * HID] = d;
    }
}

// ---------------- small matvecs: one output row per block, 256-thread K-split ----------------
__global__ __launch_bounds__(256) void k_small(
    const float* __restrict__ W_e, const float* __restrict__ b_e,
    const float* __restrict__ W_ch, const float* __restrict__ cix, const float* __restrict__ b_c,
    const float* __restrict__ W_q, const float* __restrict__ b_q,
    const float* __restrict__ u_s, const float* __restrict__ u_l,
    const float* __restrict__ h,
    float* __restrict__ erase, float* __restrict__ cand, float* __restrict__ query,
    float* __restrict__ slots_t, int doEC) {
    int tid = threadIdx.x, wid = tid >> 6, lane = tid & 63;
    int r = blockIdx.x;
    __shared__ float red[4];

    int role, rr;
    if (doEC) {
        if (r < CONTENT)                { role = 0; rr = r; }
        else if (r < 2 * CONTENT)       { role = 1; rr = r - CONTENT; }
        else if (r < 2 * CONTENT + OVERALL) { role = 2; rr = r - 2 * CONTENT; }
        else                            { role = 3 + (r - (2 * CONTENT + OVERALL)); rr = 0; }
    } else {
        if (r < OVERALL)                { role = 2; rr = r; }
        else                            { role = 3 + (r - OVERALL); rr = 0; }
    }

    const float4* h4 = (const float4*)h;
    const float4* row4;
    if (role == 0)      row4 = (const float4*)(W_e  + (size_t)rr * HID);
    else if (role == 1) row4 = (const float4*)(W_ch + (size_t)rr * HID);
    else if (role == 2) row4 = (const float4*)(W_q  + (size_t)rr * HID);
    else if (role == 3) row4 = (const float4*)u_s;
    else                row4 = (const float4*)u_l;

    float d = dot4(row4[tid], h4[tid]);
    d = wred(d);
    if (lane == 0) red[wid] = d;
    __syncthreads();
    if (tid == 0) {
        float s = red[0] + red[1] + red[2] + red[3];
        if (role == 0)      erase[rr] = sigm(s + b_e[rr]);
        else if (role == 1) cand[rr]  = fmaxf(s + cix[rr] + b_c[rr], 0.0f);
        else if (role == 2) query[rr] = s + b_q[rr];
        else if (role == 3) slots_t[1] = s;
        else                slots_t[2] = s;
    }
}

// ---------------- fused pass: lazy replay + dots + sim + exp + reading partials ----------------
// 8 rows/wave in 2 groups of 4 (short live ranges) + __launch_bounds__(256,4) (VGPR<=128)
// so m[8][2] STAYS in registers (r7 failure: default bounds -> 76 VGPR -> compiler reloaded
// memC twice). Numerator kept as 10 running scalars. part + k_redf reduction (r1: fences
// catastrophic; r6: narrow atomics serialize ~50us).
__global__ __launch_bounds__(256, 4) void k_passAB(
    const float* __restrict__ memC,
    const float* __restrict__ addrRows, const float* __restrict__ query,
    const float* __restrict__ eraseAll, const float* __restrict__ candAll,
    const float* __restrict__ addrsq, float* __restrict__ ema,
    const float* __restrict__ expAll, float* __restrict__ exp_t,
    float* __restrict__ part, const float* __restrict__ rsAll,
    const float* __restrict__ slots_t,
    const float* __restrict__ b_sh, const float* __restrict__ b_lr,
    int tstep) {
    int tid = threadIdx.x, wid = tid >> 6, lane = tid & 63;
    int gw = blockIdx.x * 4 + wid;

    __shared__ __align__(16) float lredw[4][RP];  // wave-private partial rows

    // ---- hoist memC + addr loads (8 rows = 18KB/wave in flight) ----
    float4 m[RPW][2];
    float av[RPW];
    #pragma unroll
    for (int r = 0; r < RPW; r++) {
        int i = gw + r * NWAVE_P;
        const float4* rp = (const float4*)(memC + (size_t)i * CONTENT);
        m[r][0] = rp[lane]; m[r][1] = rp[64 + lane];
        av[r] = addrRows[(size_t)i * ADDR_D + lane];
    }

    const float4 q0 = *(const float4*)(query + 4 * lane);
    const float4 q1 = *(const float4*)(query + 256 + 4 * lane);
    const float qa = query[512 + lane];
    const float qq = wred(dot4(q0, q0) + dot4(q1, q1) + qa * qa);
    const float qnorm = sqrtf(qq);
    const float bs = slots_t[1] + b_sh[0];
    const float beta = (bs > 20.0f ? bs : log1pf(expf(bs))) + 1.0f;
    const float gamma = sigm(slots_t[2] + b_lr[0]);

    // ---- replay updates u = 0 .. tstep-1 on registers (identical op order -> bit-exact) ----
    for (int u = 0; u < tstep; u++) {
        const float4 e0 = *(const float4*)(eraseAll + (size_t)u * CONTENT + 4 * lane);
        const float4 e1 = *(const float4*)(eraseAll + (size_t)u * CONTENT + 256 + 4 * lane);
        const float4 c0 = *(const float4*)(candAll + (size_t)u * CONTENT + 4 * lane);
        const float4 c1 = *(const float4*)(candAll + (size_t)u * CONTENT + 256 + 4 * lane);
        const float invp = 1.0f / rsAll[(size_t)u * RSP + OVERALL];  // ssum of step u
        const float* eb = expAll + (size_t)u * N_LOC;
        #pragma unroll
        for (int r = 0; r < RPW; r++) {
            float wv = eb[gw + r * NWAVE_P] * invp;
            UPD(m[r][0], e0, c0, wv)
            UPD(m[r][1], e1, c1, wv)
        }
    }

    // ---- per-group: dots/norms -> reduce -> sim/exp -> accumulate numerator ----
    float ax = 0, ay = 0, az = 0, aw = 0, px = 0, py = 0, pz = 0, pw = 0, avs = 0, ess = 0;
    #pragma unroll
    for (int g = 0; g < 2; g++) {
        const int r0 = 4 * g;
        float eo0 = ema[gw + (r0 + 0) * NWAVE_P];
        float eo1 = ema[gw + (r0 + 1) * NWAVE_P];
        float eo2 = ema[gw + (r0 + 2) * NWAVE_P];
        float eo3 = ema[gw + (r0 + 3) * NWAVE_P];
        float aq0 = addrsq[gw + (r0 + 0) * NWAVE_P];
        float aq1 = addrsq[gw + (r0 + 1) * NWAVE_P];
        float aq2 = addrsq[gw + (r0 + 2) * NWAVE_P];
        float aq3 = addrsq[gw + (r0 + 3) * NWAVE_P];

        float d0 = dot4(m[r0+0][0], q0) + dot4(m[r0+0][1], q1) + av[r0+0] * qa;
        float d1 = dot4(m[r0+1][0], q0) + dot4(m[r0+1][1], q1) + av[r0+1] * qa;
        float d2 = dot4(m[r0+2][0], q0) + dot4(m[r0+2][1], q1) + av[r0+2] * qa;
        float d3 = dot4(m[r0+3][0], q0) + dot4(m[r0+3][1], q1) + av[r0+3] * qa;
        float s0 = dot4(m[r0+0][0], m[r0+0][0]) + dot4(m[r0+0][1], m[r0+0][1]);
        float s1 = dot4(m[r0+1][0], m[r0+1][0]) + dot4(m[r0+1][1], m[r0+1][1]);
        float s2 = dot4(m[r0+2][0], m[r0+2][0]) + dot4(m[r0+2][1], m[r0+2][1]);
        float s3 = dot4(m[r0+3][0], m[r0+3][0]) + dot4(m[r0+3][1], m[r0+3][1]);
        #pragma unroll
        for (int mm = 32; mm; mm >>= 1) {
            d0 += __shfl_xor(d0, mm, 64); s0 += __shfl_xor(s0, mm, 64);
            d1 += __shfl_xor(d1, mm, 64); s1 += __shfl_xor(s1, mm, 64);
            d2 += __shfl_xor(d2, mm, 64); s2 += __shfl_xor(s2, mm, 64);
            d3 += __shfl_xor(d3, mm, 64); s3 += __shfl_xor(s3, mm, 64);
        }
        float sim0 = beta * d0 / (sqrtf(s0 + aq0) * qnorm + EPS_C);
        float sim1 = beta * d1 / (sqrtf(s1 + aq1) * qnorm + EPS_C);
        float sim2 = beta * d2 / (sqrtf(s2 + aq2) * qnorm + EPS_C);
        float sim3 = beta * d3 / (sqrtf(s3 + aq3) * qnorm + EPS_C);
        float es0 = expf(sim0 - gamma * eo0);
        float es1 = expf(sim1 - gamma * eo1);
        float es2 = expf(sim2 - gamma * eo2);
        float es3 = expf(sim3 - gamma * eo3);
        if (lane == 0) {
            ema[gw + (r0 + 0) * NWAVE_P] = 0.1f * eo0 + 0.9f * sim0;
            ema[gw + (r0 + 1) * NWAVE_P] = 0.1f * eo1 + 0.9f * sim1;
            ema[gw + (r0 + 2) * NWAVE_P] = 0.1f * eo2 + 0.9f * sim2;
            ema[gw + (r0 + 3) * NWAVE_P] = 0.1f * eo3 + 0.9f * sim3;
            exp_t[gw + (r0 + 0) * NWAVE_P] = es0;
            exp_t[gw + (r0 + 1) * NWAVE_P] = es1;
            exp_t[gw + (r0 + 2) * NWAVE_P] = es2;
            exp_t[gw + (r0 + 3) * NWAVE_P] = es3;
        }
        ax += es0 * m[r0+0][0].x + es1 * m[r0+1][0].x + es2 * m[r0+2][0].x + es3 * m[r0+3][0].x;
        ay += es0 * m[r0+0][0].y + es1 * m[r0+1][0].y + es2 * m[r0+2][0].y + es3 * m[r0+3][0].y;
        az += es0 * m[r0+0][0].z + es1 * m[r0+1][0].z + es2 * m[r0+2][0].z + es3 * m[r0+3][0].z;
        aw += es0 * m[r0+0][0].w + es1 * m[r0+1][0].w + es2 * m[r0+2][0].w + es3 * m[r0+3][0].w;
        px += es0 * m[r0+0][1].x + es1 * m[r0+1][1].x + es2 * m[r0+2][1].x + es3 * m[r0+3][1].x;
        py += es0 * m[r0+0][1].y + es1 * m[r0+1][1].y + es2 * m[r0+2][1].y + es3 * m[r0+3][1].y;
        pz += es0 * m[r0+0][1].z + es1 * m[r0+1][1].z + es2 * m[r0+2][1].z + es3 * m[r0+3][1].z;
        pw += es0 * m[r0+0][1].w + es1 * m[r0+1][1].w + es2 * m[r0+2][1].w + es3 * m[r0+3][1].w;
        avs += es0 * av[r0+0] + es1 * av[r0+1] + es2 * av[r0+2] + es3 * av[r0+3];
        ess += es0 + es1 + es2 + es3;
    }

    // ---- wave-private reading numerator rows (vectorized LDS stores) ----
    {
        float* lw = lredw[wid];
        *(float4*)(lw + 4 * lane) = make_float4(ax, ay, az, aw);
        *(float4*)(lw + 256 + 4 * lane) = make_float4(px, py, pz, pw);
        lw[512 + lane] = avs;
        if (lane == 0) lw[576] = ess;   // ess is wave-uniform
    }
    __syncthreads();

    // ---- combine 4 wave rows, store coalesced into part[b][c] ----
    float* pb = part + (size_t)blockIdx.x * RP;
    for (int c = tid; c < RCOLS; c += 256)
        pb[c] = lredw[0][c] + lredw[1][c] + lredw[2][c] + lredw[3][c];
}

// ---------------- final reduce: one column per block over all 1024 part rows ----------------
__global__ __launch_bounds__(256) void k_redf(const float* __restrict__ part,
                                              float* __restrict__ rs) {
    int tid = threadIdx.x, wid = tid >> 6, lane = tid & 63;
    int c = blockIdx.x;
    __shared__ float red[4];
    float acc = 0.0f;
    #pragma unroll
    for (int j = 0; j < NBLK_P / 256; j++)
        acc += part[(size_t)(tid + 256 * j) * RP + c];
    acc = wred(acc);
    if (lane == 0) red[wid] = acc;
    __syncthreads();
    if (tid == 0) rs[c] = red[0] + red[1] + red[2] + red[3];
}

// ---------------- GRU: one hidden unit per block, K-split over reading + h ----------------
__global__ __launch_bounds__(256) void k_gru(
    const float* __restrict__ W_ih, const float* __restrict__ W_hh,
    const float* __restrict__ b_ih, const float* __restrict__ b_hh,
    const float* __restrict__ gix, const float* __restrict__ rs,
    const float* __restrict__ hcur, float* __restrict__ hnew) {
    int tid = threadIdx.x, wid = tid >> 6, lane = tid & 63;
    const int k = blockIdx.x;
    __shared__ float red[4][6];

    const float invs = 1.0f / rs[OVERALL];   // ssum
    const float4* Wi0 = (const float4*)(W_ih + (size_t)k * GRU_IN + IN_D);
    const float4* Wi1 = (const float4*)(W_ih + (size_t)(k + HID) * GRU_IN + IN_D);
    const float4* Wi2 = (const float4*)(W_ih + (size_t)(k + 2 * HID) * GRU_IN + IN_D);
    const float4* Wh0 = (const float4*)(W_hh + (size_t)k * HID);
    const float4* Wh1 = (const float4*)(W_hh + (size_t)(k + HID) * HID);
    const float4* Wh2 = (const float4*)(W_hh + (size_t)(k + 2 * HID) * HID);

    float gi0 = 0, gi1 = 0, gi2 = 0;
    if (tid < OVERALL / 4) {            // 144 float4s of reading
        float4 v = ((const float4*)rs)[tid];
        v.x *= invs; v.y *= invs; v.z *= invs; v.w *= invs;
        gi0 = dot4(Wi0[tid], v); gi1 = dot4(Wi1[tid], v); gi2 = dot4(Wi2[tid], v);
    }
    float4 hv = ((const float4*)hcur)[tid];  // HID = 256 float4s
    float gh0 = dot4(Wh0[tid], hv);
    float gh1 = dot4(Wh1[tid], hv);
    float gh2 = dot4(Wh2[tid], hv);

    #pragma unroll
    for (int m = 32; m; m >>= 1) {
        gi0 += __shfl_xor(gi0, m, 64); gi1 += __shfl_xor(gi1, m, 64); gi2 += __shfl_xor(gi2, m, 64);
        gh0 += __shfl_xor(gh0, m, 64); gh1 += __shfl_xor(gh1, m, 64); gh2 += __shfl_xor(gh2, m, 64);
    }
    if (lane == 0) {
        red[wid][0] = gi0; red[wid][1] = gi1; red[wid][2] = gi2;
        red[wid][3] = gh0; red[wid][4] = gh1; red[wid][5] = gh2;
    }
    __syncthreads();
    if (tid == 0) {
        float a0 = red[0][0] + red[1][0] + red[2][0] + red[3][0] + gix[k];
        float a1 = red[0][1] + red[1][1] + red[2][1] + red[3][1] + gix[HID + k];
        float a2 = red[0][2] + red[1][2] + red[2][2] + red[3][2] + gix[2 * HID + k];
        float a3 = red[0][3] + red[1][3] + red[2][3] + red[3][3];
        float a4 = red[0][4] + red[1][4] + red[2][4] + red[3][4];
        float a5 = red[0][5] + red[1][5] + red[2][5] + red[3][5];
        float r = sigm(a0 + b_ih[k] + a3 + b_hh[k]);
        float z = sigm(a1 + b_ih[HID + k] + a4 + b_hh[HID + k]);
        float n = tanhf(a2 + b_ih[2 * HID + k] + r * (a5 + b_hh[2 * HID + k]));
        hnew[k] = (1.0f - z) * n + z * hcur[k];
    }
}

// ---------------- output: copy h, logits + log_softmax ----------------
__global__ __launch_bounds__(256) void k_out(const float* __restrict__ W_o,
                                             const float* __restrict__ b_o,
                                             const float* __restrict__ h,
                                             float* __restrict__ out) {
    int tid = threadIdx.x, wid = tid >> 6, lane = tid & 63;
    __shared__ float lg[OUT_D];
    for (int j = tid; j < HID; j += 256) out[j] = h[j];
    const float4* h4 = (const float4*)h;
    for (int u = wid; u < OUT_D; u += 4) {
        const float4* row = (const float4*)(W_o + (size_t)u * HID);
        float d = 0.0f;
        #pragma unroll
        for (int i = 0; i < 4; i++) d += dot4(row[lane + 64 * i], h4[lane + 64 * i]);
        d = wred(d);
        if (lane == 0) lg[u] = d + b_o[u];
    }
    __syncthreads();
    if (tid == 0) {
        float m = -1e30f;
        for (int u = 0; u < OUT_D; u++) m = fmaxf(m, lg[u]);
        float se = 0.0f;
        for (int u = 0; u < OUT_D; u++) se += expf(lg[u] - m);
        float lse = m + logf(se);
        for (int u = 0; u < OUT_D; u++) out[HID + u] = lg[u] - lse;
    }
}

extern "C" void kernel_launch(void* const* d_in, const int* in_sizes, int n_in,
                              void* d_out, int out_size, void* d_ws, size_t ws_size,
                              hipStream_t stream) {
    const float* x    = (const float*)d_in[0];
    const float* h0   = (const float*)d_in[1];
    const float* memC = (const float*)d_in[2];
    const float* addrR= (const float*)d_in[3];
    const float* W_q  = (const float*)d_in[4];
    const float* b_q  = (const float*)d_in[5];
    const float* u_s  = (const float*)d_in[6];
    const float* b_s  = (const float*)d_in[7];
    const float* u_l  = (const float*)d_in[8];
    const float* b_l  = (const float*)d_in[9];
    const float* W_e  = (const float*)d_in[10];
    const float* b_e  = (const float*)d_in[11];
    const float* W_ch = (const float*)d_in[12];
    const float* W_ci = (const float*)d_in[13];
    const float* b_c  = (const float*)d_in[14];
    const float* W_ih = (const float*)d_in[15];
    const float* W_hh = (const float*)d_in[16];
    const float* b_ih = (const float*)d_in[17];
    const float* b_hh = (const float*)d_in[18];
    const float* W_o  = (const float*)d_in[19];
    const float* b_o  = (const float*)d_in[20];

    // workspace layout (floats)
    const size_t SM_ADDRSQ = 0;
    const size_t SM_EXPA   = SM_ADDRSQ + N_LOC;                  // NSTEPS * N_LOC
    const size_t SM_EMA    = SM_EXPA + (size_t)NSTEPS * N_LOC;
    const size_t SM_QUERY  = SM_EMA + N_LOC;
    const size_t SM_ER     = SM_QUERY + NSTEPS * OVERALL;
    const size_t SM_CAND   = SM_ER + NSTEPS * CONTENT;
    const size_t SM_H      = SM_CAND + NSTEPS * CONTENT;
    const size_t SM_SLOTS  = SM_H + (NSTEPS + 1) * HID;
    const size_t SM_RS     = SM_SLOTS + NSTEPS * 8;              // NSTEPS * RSP
    const size_t SM_GIX    = SM_RS + (size_t)NSTEPS * RSP;       // 3*HID
    const size_t SM_CIX    = SM_GIX + 3 * HID;                   // CONTENT
    const size_t SM_PART   = SM_CIX + CONTENT;                   // NBLK_P * RP

    float* sb = (float*)d_ws;
    float* addrsq  = sb + SM_ADDRSQ;
    float* exp_all = sb + SM_EXPA;
    float* ema     = sb + SM_EMA;
    float* query   = sb + SM_QUERY;
    float* erase   = sb + SM_ER;
    float* cand    = sb + SM_CAND;
    float* H       = sb + SM_H;
    float* slots   = sb + SM_SLOTS;
    float* rsAll   = sb + SM_RS;
    float* gix     = sb + SM_GIX;
    float* cix     = sb + SM_CIX;
    float* part    = sb + SM_PART;

    k_init<<<512, 256, 0, stream>>>(addrR, addrsq, ema);
    k_pre<<<3 * HID + CONTENT, 64, 0, stream>>>(W_ih, W_ci, x, gix, cix);
    k_small<<<OVERALL + 2, 256, 0, stream>>>(
        W_e, b_e, W_ch, cix, b_c, W_q, b_q, u_s, u_l, h0,
        erase, cand, query, slots, 0);

    const float* hcur = h0;
    for (int t = 0; t < NSTEPS; t++) {
        k_passAB<<<NBLK_P, 256, 0, stream>>>(
            memC, addrR,
            query + t * OVERALL,
            erase, cand,
            addrsq, ema,
            exp_all, exp_all + (size_t)t * N_LOC,
            part, rsAll,
            slots + t * 8, b_s, b_l,
            t);
        float* rs_t = rsAll + (size_t)t * RSP;
        k_redf<<<RCOLS, 256, 0, stream>>>(part, rs_t);
        float* hn = H + (t + 1) * HID;
        k_gru<<<HID, 256, 0, stream>>>(W_ih, W_hh, b_ih, b_hh, gix,
                                       rs_t, hcur, hn);
        if (t < NSTEPS - 1) {
            k_small<<<2 * CONTENT + OVERALL + 2, 256, 0, stream>>>(
                W_e, b_e, W_ch, cix, b_c, W_q, b_q, u_s, u_l, hn,
                erase + t * CONTENT, cand + t * CONTENT,
                query + (t + 1) * OVERALL, slots + (t + 1) * 8, 1);
        }
        hcur = hn;
    }
    k_out<<<1, 256, 0, stream>>>(W_o, b_o, hcur, (float*)d_out);
}

// Round 9
// 488.626 us; speedup vs baseline: 1.6573x; 1.0571x over previous
//
#include <hip/hip_runtime.h>
#include <math.h>

#define N_LOC 32768
#define CONTENT 512
#define ADDR_D 64
#define HID 1024
#define IN_D 256
#define OUT_D 10
#define OVERALL 576
#define GRU_IN 832
#define EPS_C 1e-7f
#define NSTEPS 8

#define NBLK_P 2048
#define NWAVE_P (NBLK_P * 4)     // 8192 waves; 4 rows/wave — measured optimum.
                                 // r7/r8: 8 rows/wave = neutral-to-worse (passAB is
                                 // fabric-latency-bound, not ILP-bound).
#define RCOLS (OVERALL + 1)      // 576 reading cols + 1 ssum col
#define RP 580                   // padded part-row length (16B-aligned rows)
#define RSP 580                  // padded rs-row length

__device__ __forceinline__ float wred(float v) {
    #pragma unroll
    for (int m = 32; m; m >>= 1) v += __shfl_xor(v, m, 64);
    return v;
}
__device__ __forceinline__ float sigm(float x) { return 1.0f / (1.0f + expf(-x)); }
__device__ __forceinline__ float dot4(float4 a, float4 b) {
    return a.x * b.x + a.y * b.y + a.z * b.z + a.w * b.w;
}

// ---------------- init: addr row norms^2, zero ema ----------------
__global__ __launch_bounds__(256) void k_init(const float* __restrict__ addrRows,
                                              float* __restrict__ addrsq,
                                              float* __restrict__ ema) {
    int tid = threadIdx.x, wid = tid >> 6, lane = tid & 63;
    int gid = blockIdx.x * 256 + tid;
    if (gid < N_LOC) ema[gid] = 0.0f;
    for (int i = blockIdx.x * 4 + wid; i < N_LOC; i += gridDim.x * 4) {
        float a = addrRows[(size_t)i * ADDR_D + lane];
        float sq = wred(a * a);
        if (lane == 0) addrsq[i] = sq;
    }
}

// ---------------- precompute (once): gix = W_ih[:, :256] @ x ; cix = W_ci @ x ----------------
// x is constant across all steps; gru/small were re-doing this every step.
__global__ __launch_bounds__(64) void k_pre(const float* __restrict__ W_ih,
                                            const float* __restrict__ W_ci,
                                            const float* __restrict__ x,
                                            float* __restrict__ gix,
                                            float* __restrict__ cix) {
    int tid = threadIdx.x;
    int r = blockIdx.x;
    const float4* x4 = (const float4*)x;
    const float4* row;
    if (r < 3 * HID) row = (const float4*)(W_ih + (size_t)r * GRU_IN);
    else             row = (const float4*)(W_ci + (size_t)(r - 3 * HID) * IN_D);
    float d = dot4(row[tid], x4[tid]);       // IN_D = 256 = 64 float4s
    d = wred(d);
    if (tid == 0) {
        if (r < 3 * HID) gix[r] = d;
        else             cix[r - 3 * HID] = d;
    }
}

// ---------------- small matvecs: one output row per block, 256-thread K-split ----------------
// roles: 0=erase, 1=cand (uses precomputed cix), 2=query, 3=u_s.h, 4=u_l.h
__global__ __launch_bounds__(256) void k_small(
    const float* __restrict__ W_e, const float* __restrict__ b_e,
    const float* __restrict__ W_ch, const float* __restrict__ cix, const float* __restrict__ b_c,
    const float* __restrict__ W_q, const float* __restrict__ b_q,
    const float* __restrict__ u_s, const float* __restrict__ u_l,
    const float* __restrict__ h,
    float* __restrict__ erase, float* __restrict__ cand, float* __restrict__ query,
    float* __restrict__ slots_t, int doEC) {
    int tid = threadIdx.x, wid = tid >> 6, lane = tid & 63;
    int r = blockIdx.x;
    __shared__ float red[4];

    int role, rr;
    if (doEC) {
        if (r < CONTENT)                { role = 0; rr = r; }
        else if (r < 2 * CONTENT)       { role = 1; rr = r - CONTENT; }
        else if (r < 2 * CONTENT + OVERALL) { role = 2; rr = r - 2 * CONTENT; }
        else                            { role = 3 + (r - (2 * CONTENT + OVERALL)); rr = 0; }
    } else {
        if (r < OVERALL)                { role = 2; rr = r; }
        else                            { role = 3 + (r - OVERALL); rr = 0; }
    }

    const float4* h4 = (const float4*)h;
    const float4* row4;
    if (role == 0)      row4 = (const float4*)(W_e  + (size_t)rr * HID);
    else if (role == 1) row4 = (const float4*)(W_ch + (size_t)rr * HID);
    else if (role == 2) row4 = (const float4*)(W_q  + (size_t)rr * HID);
    else if (role == 3) row4 = (const float4*)u_s;
    else                row4 = (const float4*)u_l;

    float d = dot4(row4[tid], h4[tid]);     // HID = 256 float4s, one per thread
    d = wred(d);
    if (lane == 0) red[wid] = d;
    __syncthreads();
    if (tid == 0) {
        float s = red[0] + red[1] + red[2] + red[3];
        if (role == 0)      erase[rr] = sigm(s + b_e[rr]);
        else if (role == 1) cand[rr]  = fmaxf(s + cix[rr] + b_c[rr], 0.0f);
        else if (role == 2) query[rr] = s + b_q[rr];
        else if (role == 3) slots_t[1] = s;
        else                slots_t[2] = s;
    }
}

// ---------------- fused pass: full-lazy update replay + dots + sim + exp + reading partials
// mem is NEVER written: pass t rebuilds mem_t in registers from read-only memC by replaying
// updates u=0..t-1 (scalar w_u per row + 4KB e_u/c_u vectors). Verified optimum (r4, 490us).
// Design ledger: NO __threadfence (r1: L2 wb/inv storm, 13x); NO narrow atomics (r6: 577-float
// target = 9 cachelines, ~50us serialization); 4 rows/wave (r7/r8: 8 rows neutral-to-worse —
// kernel is fabric-latency-bound at ~1.4 TB/s effective, FETCH ~41.7MB with ~22MB cross-pass
// L2 persistence); part + k_redf behind kernel boundary is the correct global reduction.
__global__ __launch_bounds__(256) void k_passAB(
    const float* __restrict__ memC,
    const float* __restrict__ addrRows, const float* __restrict__ query,
    const float* __restrict__ eraseAll, const float* __restrict__ candAll,
    const float* __restrict__ addrsq, float* __restrict__ ema,
    const float* __restrict__ expAll, float* __restrict__ exp_t,
    float* __restrict__ part, const float* __restrict__ rsAll,
    const float* __restrict__ slots_t,
    const float* __restrict__ b_sh, const float* __restrict__ b_lr,
    int tstep) {
    int tid = threadIdx.x, wid = tid >> 6, lane = tid & 63;
    int gw = blockIdx.x * 4 + wid;
    const int i0 = gw;
    const int i1 = gw + NWAVE_P;
    const int i2 = gw + 2 * NWAVE_P;
    const int i3 = gw + 3 * NWAVE_P;

    __shared__ __align__(16) float lredw[4][RP];  // wave-private partial rows

    // ---- hoist ALL global loads (4 mem rows = 9KB/wave in flight) ----
    const float4* r0p = (const float4*)(memC + (size_t)i0 * CONTENT);
    const float4* r1p = (const float4*)(memC + (size_t)i1 * CONTENT);
    const float4* r2p = (const float4*)(memC + (size_t)i2 * CONTENT);
    const float4* r3p = (const float4*)(memC + (size_t)i3 * CONTENT);
    float4 m00 = r0p[lane], m01 = r0p[64 + lane];
    float4 m10 = r1p[lane], m11 = r1p[64 + lane];
    float4 m20 = r2p[lane], m21 = r2p[64 + lane];
    float4 m30 = r3p[lane], m31 = r3p[64 + lane];
    float av0 = addrRows[(size_t)i0 * ADDR_D + lane];
    float av1 = addrRows[(size_t)i1 * ADDR_D + lane];
    float av2 = addrRows[(size_t)i2 * ADDR_D + lane];
    float av3 = addrRows[(size_t)i3 * ADDR_D + lane];
    float eo0 = ema[i0], eo1 = ema[i1], eo2 = ema[i2], eo3 = ema[i3];
    float asq0 = addrsq[i0], asq1 = addrsq[i1], asq2 = addrsq[i2], asq3 = addrsq[i3];

    const float4 q0 = *(const float4*)(query + 4 * lane);
    const float4 q1 = *(const float4*)(query + 256 + 4 * lane);
    const float qa = query[512 + lane];
    const float qq = wred(dot4(q0, q0) + dot4(q1, q1) + qa * qa);
    const float qnorm = sqrtf(qq);
    const float bs = slots_t[1] + b_sh[0];
    const float beta = (bs > 20.0f ? bs : log1pf(expf(bs))) + 1.0f;
    const float gamma = sigm(slots_t[2] + b_lr[0]);

    // ---- replay updates u = 0 .. tstep-1 on registers (identical op order -> bit-exact) ----
    #define UPD(m, e, c, wv) \
        m.x = m.x * (1.0f - wv * e.x) + wv * c.x; \
        m.y = m.y * (1.0f - wv * e.y) + wv * c.y; \
        m.z = m.z * (1.0f - wv * e.z) + wv * c.z; \
        m.w = m.w * (1.0f - wv * e.w) + wv * c.w;
    for (int u = 0; u < tstep; u++) {
        const float4 e0 = *(const float4*)(eraseAll + (size_t)u * CONTENT + 4 * lane);
        const float4 e1 = *(const float4*)(eraseAll + (size_t)u * CONTENT + 256 + 4 * lane);
        const float4 c0 = *(const float4*)(candAll + (size_t)u * CONTENT + 4 * lane);
        const float4 c1 = *(const float4*)(candAll + (size_t)u * CONTENT + 256 + 4 * lane);
        const float invp = 1.0f / rsAll[(size_t)u * RSP + OVERALL];  // ssum of step u
        const float* eb = expAll + (size_t)u * N_LOC;
        const float wv0 = eb[i0] * invp;
        const float wv1 = eb[i1] * invp;
        const float wv2 = eb[i2] * invp;
        const float wv3 = eb[i3] * invp;
        UPD(m00, e0, c0, wv0) UPD(m01, e1, c1, wv0)
        UPD(m10, e0, c0, wv1) UPD(m11, e1, c1, wv1)
        UPD(m20, e0, c0, wv2) UPD(m21, e1, c1, wv2)
        UPD(m30, e0, c0, wv3) UPD(m31, e1, c1, wv3)
    }
    #undef UPD

    // ---- dots + norms: 8 interleaved reduction chains ----
    float d0 = dot4(m00, q0) + dot4(m01, q1) + av0 * qa;
    float d1 = dot4(m10, q0) + dot4(m11, q1) + av1 * qa;
    float d2 = dot4(m20, q0) + dot4(m21, q1) + av2 * qa;
    float d3 = dot4(m30, q0) + dot4(m31, q1) + av3 * qa;
    float s0 = dot4(m00, m00) + dot4(m01, m01);
    float s1 = dot4(m10, m10) + dot4(m11, m11);
    float s2 = dot4(m20, m20) + dot4(m21, m21);
    float s3 = dot4(m30, m30) + dot4(m31, m31);
    #pragma unroll
    for (int m = 32; m; m >>= 1) {
        d0 += __shfl_xor(d0, m, 64); s0 += __shfl_xor(s0, m, 64);
        d1 += __shfl_xor(d1, m, 64); s1 += __shfl_xor(s1, m, 64);
        d2 += __shfl_xor(d2, m, 64); s2 += __shfl_xor(s2, m, 64);
        d3 += __shfl_xor(d3, m, 64); s3 += __shfl_xor(s3, m, 64);
    }
    float sim0 = beta * d0 / (sqrtf(s0 + asq0) * qnorm + EPS_C);
    float sim1 = beta * d1 / (sqrtf(s1 + asq1) * qnorm + EPS_C);
    float sim2 = beta * d2 / (sqrtf(s2 + asq2) * qnorm + EPS_C);
    float sim3 = beta * d3 / (sqrtf(s3 + asq3) * qnorm + EPS_C);
    float es0 = expf(sim0 - gamma * eo0);
    float es1 = expf(sim1 - gamma * eo1);
    float es2 = expf(sim2 - gamma * eo2);
    float es3 = expf(sim3 - gamma * eo3);
    if (lane == 0) {
        ema[i0] = 0.1f * eo0 + 0.9f * sim0;
        ema[i1] = 0.1f * eo1 + 0.9f * sim1;
        ema[i2] = 0.1f * eo2 + 0.9f * sim2;
        ema[i3] = 0.1f * eo3 + 0.9f * sim3;
        exp_t[i0] = es0; exp_t[i1] = es1; exp_t[i2] = es2; exp_t[i3] = es3;
    }

    // ---- wave-private reading numerator rows (vectorized LDS stores) ----
    float* lw = lredw[wid];
    float4 va = make_float4(
        es0 * m00.x + es1 * m10.x + es2 * m20.x + es3 * m30.x,
        es0 * m00.y + es1 * m10.y + es2 * m20.y + es3 * m30.y,
        es0 * m00.z + es1 * m10.z + es2 * m20.z + es3 * m30.z,
        es0 * m00.w + es1 * m10.w + es2 * m20.w + es3 * m30.w);
    *(float4*)(lw + 4 * lane) = va;
    float4 vb = make_float4(
        es0 * m01.x + es1 * m11.x + es2 * m21.x + es3 * m31.x,
        es0 * m01.y + es1 * m11.y + es2 * m21.y + es3 * m31.y,
        es0 * m01.z + es1 * m11.z + es2 * m21.z + es3 * m31.z,
        es0 * m01.w + es1 * m11.w + es2 * m21.w + es3 * m31.w);
    *(float4*)(lw + 256 + 4 * lane) = vb;
    lw[512 + lane] = es0 * av0 + es1 * av1 + es2 * av2 + es3 * av3;
    if (lane == 0) lw[576] = es0 + es1 + es2 + es3;   // es are wave-uniform
    __syncthreads();

    // ---- combine 4 wave rows, store coalesced into part[b][c] ----
    float* pb = part + (size_t)blockIdx.x * RP;
    for (int c = tid; c < RCOLS; c += 256)
        pb[c] = lredw[0][c] + lredw[1][c] + lredw[2][c] + lredw[3][c];
}

// ---------------- final reduce: one column per block over all 2048 part rows ----------------
__global__ __launch_bounds__(256) void k_redf(const float* __restrict__ part,
                                              float* __restrict__ rs) {
    int tid = threadIdx.x, wid = tid >> 6, lane = tid & 63;
    int c = blockIdx.x;
    __shared__ float red[4];
    float acc = 0.0f;
    #pragma unroll
    for (int j = 0; j < NBLK_P / 256; j++)
        acc += part[(size_t)(tid + 256 * j) * RP + c];
    acc = wred(acc);
    if (lane == 0) red[wid] = acc;
    __syncthreads();
    if (tid == 0) rs[c] = red[0] + red[1] + red[2] + red[3];
}

// ---------------- GRU: one hidden unit per block, K-split over reading + h ----------------
__global__ __launch_bounds__(256) void k_gru(
    const float* __restrict__ W_ih, const float* __restrict__ W_hh,
    const float* __restrict__ b_ih, const float* __restrict__ b_hh,
    const float* __restrict__ gix, const float* __restrict__ rs,
    const float* __restrict__ hcur, float* __restrict__ hnew) {
    int tid = threadIdx.x, wid = tid >> 6, lane = tid & 63;
    const int k = blockIdx.x;
    __shared__ float red[4][6];

    const float invs = 1.0f / rs[OVERALL];   // ssum
    const float4* Wi0 = (const float4*)(W_ih + (size_t)k * GRU_IN + IN_D);
    const float4* Wi1 = (const float4*)(W_ih + (size_t)(k + HID) * GRU_IN + IN_D);
    const float4* Wi2 = (const float4*)(W_ih + (size_t)(k + 2 * HID) * GRU_IN + IN_D);
    const float4* Wh0 = (const float4*)(W_hh + (size_t)k * HID);
    const float4* Wh1 = (const float4*)(W_hh + (size_t)(k + HID) * HID);
    const float4* Wh2 = (const float4*)(W_hh + (size_t)(k + 2 * HID) * HID);

    float gi0 = 0, gi1 = 0, gi2 = 0;
    if (tid < OVERALL / 4) {            // 144 float4s of reading
        float4 v = ((const float4*)rs)[tid];
        v.x *= invs; v.y *= invs; v.z *= invs; v.w *= invs;
        gi0 = dot4(Wi0[tid], v); gi1 = dot4(Wi1[tid], v); gi2 = dot4(Wi2[tid], v);
    }
    float4 hv = ((const float4*)hcur)[tid];  // HID = 256 float4s
    float gh0 = dot4(Wh0[tid], hv);
    float gh1 = dot4(Wh1[tid], hv);
    float gh2 = dot4(Wh2[tid], hv);

    #pragma unroll
    for (int m = 32; m; m >>= 1) {
        gi0 += __shfl_xor(gi0, m, 64); gi1 += __shfl_xor(gi1, m, 64); gi2 += __shfl_xor(gi2, m, 64);
        gh0 += __shfl_xor(gh0, m, 64); gh1 += __shfl_xor(gh1, m, 64); gh2 += __shfl_xor(gh2, m, 64);
    }
    if (lane == 0) {
        red[wid][0] = gi0; red[wid][1] = gi1; red[wid][2] = gi2;
        red[wid][3] = gh0; red[wid][4] = gh1; red[wid][5] = gh2;
    }
    __syncthreads();
    if (tid == 0) {
        float a0 = red[0][0] + red[1][0] + red[2][0] + red[3][0] + gix[k];
        float a1 = red[0][1] + red[1][1] + red[2][1] + red[3][1] + gix[HID + k];
        float a2 = red[0][2] + red[1][2] + red[2][2] + red[3][2] + gix[2 * HID + k];
        float a3 = red[0][3] + red[1][3] + red[2][3] + red[3][3];
        float a4 = red[0][4] + red[1][4] + red[2][4] + red[3][4];
        float a5 = red[0][5] + red[1][5] + red[2][5] + red[3][5];
        float r = sigm(a0 + b_ih[k] + a3 + b_hh[k]);
        float z = sigm(a1 + b_ih[HID + k] + a4 + b_hh[HID + k]);
        float n = tanhf(a2 + b_ih[2 * HID + k] + r * (a5 + b_hh[2 * HID + k]));
        hnew[k] = (1.0f - z) * n + z * hcur[k];
    }
}

// ---------------- output: copy h, logits + log_softmax ----------------
__global__ __launch_bounds__(256) void k_out(const float* __restrict__ W_o,
                                             const float* __restrict__ b_o,
                                             const float* __restrict__ h,
                                             float* __restrict__ out) {
    int tid = threadIdx.x, wid = tid >> 6, lane = tid & 63;
    __shared__ float lg[OUT_D];
    for (int j = tid; j < HID; j += 256) out[j] = h[j];
    const float4* h4 = (const float4*)h;
    for (int u = wid; u < OUT_D; u += 4) {
        const float4* row = (const float4*)(W_o + (size_t)u * HID);
        float d = 0.0f;
        #pragma unroll
        for (int i = 0; i < 4; i++) d += dot4(row[lane + 64 * i], h4[lane + 64 * i]);
        d = wred(d);
        if (lane == 0) lg[u] = d + b_o[u];
    }
    __syncthreads();
    if (tid == 0) {
        float m = -1e30f;
        for (int u = 0; u < OUT_D; u++) m = fmaxf(m, lg[u]);
        float se = 0.0f;
        for (int u = 0; u < OUT_D; u++) se += expf(lg[u] - m);
        float lse = m + logf(se);
        for (int u = 0; u < OUT_D; u++) out[HID + u] = lg[u] - lse;
    }
}

extern "C" void kernel_launch(void* const* d_in, const int* in_sizes, int n_in,
                              void* d_out, int out_size, void* d_ws, size_t ws_size,
                              hipStream_t stream) {
    const float* x    = (const float*)d_in[0];
    const float* h0   = (const float*)d_in[1];
    const float* memC = (const float*)d_in[2];
    const float* addrR= (const float*)d_in[3];
    const float* W_q  = (const float*)d_in[4];
    const float* b_q  = (const float*)d_in[5];
    const float* u_s  = (const float*)d_in[6];
    const float* b_s  = (const float*)d_in[7];
    const float* u_l  = (const float*)d_in[8];
    const float* b_l  = (const float*)d_in[9];
    const float* W_e  = (const float*)d_in[10];
    const float* b_e  = (const float*)d_in[11];
    const float* W_ch = (const float*)d_in[12];
    const float* W_ci = (const float*)d_in[13];
    const float* b_c  = (const float*)d_in[14];
    const float* W_ih = (const float*)d_in[15];
    const float* W_hh = (const float*)d_in[16];
    const float* b_ih = (const float*)d_in[17];
    const float* b_hh = (const float*)d_in[18];
    const float* W_o  = (const float*)d_in[19];
    const float* b_o  = (const float*)d_in[20];

    // workspace layout (floats) — mem is never written, no mem buffer needed
    const size_t SM_ADDRSQ = 0;
    const size_t SM_EXPA   = SM_ADDRSQ + N_LOC;                  // NSTEPS * N_LOC
    const size_t SM_EMA    = SM_EXPA + (size_t)NSTEPS * N_LOC;
    const size_t SM_QUERY  = SM_EMA + N_LOC;
    const size_t SM_ER     = SM_QUERY + NSTEPS * OVERALL;
    const size_t SM_CAND   = SM_ER + NSTEPS * CONTENT;
    const size_t SM_H      = SM_CAND + NSTEPS * CONTENT;
    const size_t SM_SLOTS  = SM_H + (NSTEPS + 1) * HID;
    const size_t SM_RS     = SM_SLOTS + NSTEPS * 8;              // NSTEPS * RSP
    const size_t SM_GIX    = SM_RS + (size_t)NSTEPS * RSP;       // 3*HID
    const size_t SM_CIX    = SM_GIX + 3 * HID;                   // CONTENT
    const size_t SM_PART   = SM_CIX + CONTENT;                   // NBLK_P * RP

    float* sb = (float*)d_ws;
    float* addrsq  = sb + SM_ADDRSQ;
    float* exp_all = sb + SM_EXPA;
    float* ema     = sb + SM_EMA;
    float* query   = sb + SM_QUERY;
    float* erase   = sb + SM_ER;
    float* cand    = sb + SM_CAND;
    float* H       = sb + SM_H;
    float* slots   = sb + SM_SLOTS;
    float* rsAll   = sb + SM_RS;
    float* gix     = sb + SM_GIX;
    float* cix     = sb + SM_CIX;
    float* part    = sb + SM_PART;

    k_init<<<512, 256, 0, stream>>>(addrR, addrsq, ema);
    k_pre<<<3 * HID + CONTENT, 64, 0, stream>>>(W_ih, W_ci, x, gix, cix);
    k_small<<<OVERALL + 2, 256, 0, stream>>>(
        W_e, b_e, W_ch, cix, b_c, W_q, b_q, u_s, u_l, h0,
        erase, cand, query, slots, 0);

    const float* hcur = h0;
    for (int t = 0; t < NSTEPS; t++) {
        k_passAB<<<NBLK_P, 256, 0, stream>>>(
            memC, addrR,
            query + t * OVERALL,
            erase, cand,
            addrsq, ema,
            exp_all, exp_all + (size_t)t * N_LOC,
            part, rsAll,
            slots + t * 8, b_s, b_l,
            t);
        float* rs_t = rsAll + (size_t)t * RSP;
        k_redf<<<RCOLS, 256, 0, stream>>>(part, rs_t);
        float* hn = H + (t + 1) * HID;
        k_gru<<<HID, 256, 0, stream>>>(W_ih, W_hh, b_ih, b_hh, gix,
                                       rs_t, hcur, hn);
        if (t < NSTEPS - 1) {
            k_small<<<2 * CONTENT + OVERALL + 2, 256, 0, stream>>>(
                W_e, b_e, W_ch, cix, b_c, W_q, b_q, u_s, u_l, hn,
                erase + t * CONTENT, cand + t * CONTENT,
                query + (t + 1) * OVERALL, slots + (t + 1) * 8, 1);
        }
        hcur = hn;
    }
    k_out<<<1, 256, 0, stream>>>(W_o, b_o, hcur, (float*)d_out);
}